// Round 6
// baseline (1130.986 us; speedup 1.0000x reference)
//
#include <hip/hip_runtime.h>
#include <hip/hip_fp16.h>

// GCN 2-layer: x[N,128] -> (x@W1) agg -> relu -> (@W2) agg -> out[N,32]
// agg[i] = dinv[i] * sum_{j in in(i) + self} h[j]*dinv[j]  (+ bias)
// Edges bucketed by dst (256 nodes/bucket) via counting scatter; aggregation
// is edge-parallel with per-bucket fp32 accumulators in LDS (no CSR sort).
// GEMMs on MFMA (16x16x32 f16, fp32 accum). Hidden tensors fp16.

#define IN_C 128
#define HID 64
#define OUTC 32
#define BSH 8            // bucket shift (256 nodes per bucket)
#define BSZ 256
#define NSLOT 512        // bucket slots in hist/scan (>= #buckets=391)
#define EPB 16384        // edges per histogram/scatter block

typedef _Float16 half8 __attribute__((ext_vector_type(8)));
typedef float f32x4 __attribute__((ext_vector_type(4)));

static __host__ __device__ __forceinline__ size_t szt(int a) { return (size_t)a; }

// ---- pass 1: per-block bucket histograms (512 slots) -----------------------
__global__ __launch_bounds__(256) void k_hist(const int* __restrict__ dst, int E,
                                              int* __restrict__ hist) {
  __shared__ int h[NSLOT];
  int tid = threadIdx.x;
  h[tid] = 0; h[tid + 256] = 0;
  __syncthreads();
  int e0 = blockIdx.x * EPB;
  int e1 = min(e0 + EPB, E);
  for (int i = e0 + tid; i < e1; i += 256) atomicAdd(&h[dst[i] >> BSH], 1);
  __syncthreads();
  hist[blockIdx.x * NSLOT + tid] = h[tid];
  hist[blockIdx.x * NSLOT + tid + 256] = h[tid + 256];
}

// ---- pass 2: column scan, thread k owns columns 2k,2k+1 --------------------
__global__ __launch_bounds__(256) void k_scan(int* __restrict__ hist, int B,
                                              int* __restrict__ bucket_base,
                                              int* __restrict__ bucket_count) {
  int k = threadIdx.x;
  int run0 = 0, run1 = 0;
  int b = 0;
  for (; b + 4 <= B; b += 4) {
    int2 v0 = *reinterpret_cast<const int2*>(&hist[(b + 0) * NSLOT + 2 * k]);
    int2 v1 = *reinterpret_cast<const int2*>(&hist[(b + 1) * NSLOT + 2 * k]);
    int2 v2 = *reinterpret_cast<const int2*>(&hist[(b + 2) * NSLOT + 2 * k]);
    int2 v3 = *reinterpret_cast<const int2*>(&hist[(b + 3) * NSLOT + 2 * k]);
    *reinterpret_cast<int2*>(&hist[(b + 0) * NSLOT + 2 * k]) = make_int2(run0, run1);
    run0 += v0.x; run1 += v0.y;
    *reinterpret_cast<int2*>(&hist[(b + 1) * NSLOT + 2 * k]) = make_int2(run0, run1);
    run0 += v1.x; run1 += v1.y;
    *reinterpret_cast<int2*>(&hist[(b + 2) * NSLOT + 2 * k]) = make_int2(run0, run1);
    run0 += v2.x; run1 += v2.y;
    *reinterpret_cast<int2*>(&hist[(b + 3) * NSLOT + 2 * k]) = make_int2(run0, run1);
    run0 += v3.x; run1 += v3.y;
  }
  for (; b < B; ++b) {
    int2 v = *reinterpret_cast<const int2*>(&hist[b * NSLOT + 2 * k]);
    *reinterpret_cast<int2*>(&hist[b * NSLOT + 2 * k]) = make_int2(run0, run1);
    run0 += v.x; run1 += v.y;
  }
  __shared__ int sc[256];
  int s = run0 + run1;
  sc[k] = s;
  __syncthreads();
  for (int o = 1; o < 256; o <<= 1) {   // inclusive Hillis-Steele over pairs
    int v = (k >= o) ? sc[k - o] : 0;
    __syncthreads();
    sc[k] += v;
    __syncthreads();
  }
  int base = sc[k] - s;                 // exclusive over pair blocks
  bucket_base[2 * k] = base;
  bucket_base[2 * k + 1] = base + run0;
  bucket_count[2 * k] = run0;
  bucket_count[2 * k + 1] = run1;
}

// ---- pass 3: scatter packed edges to per-(block,bucket) reserved ranges ----
__global__ __launch_bounds__(256) void k_scatter(const int* __restrict__ src,
                                                 const int* __restrict__ dst, int E,
                                                 const int* __restrict__ hist,
                                                 const int* __restrict__ bucket_base,
                                                 int* __restrict__ bedges) {
  __shared__ int off[NSLOT];
  int tid = threadIdx.x;
  off[tid] = hist[blockIdx.x * NSLOT + tid] + bucket_base[tid];
  off[tid + 256] = hist[blockIdx.x * NSLOT + tid + 256] + bucket_base[tid + 256];
  __syncthreads();
  int e0 = blockIdx.x * EPB;
  int e1 = min(e0 + EPB, E);
  for (int i = e0 + tid; i < e1; i += 256) {
    int d = dst[i], s = src[i];
    int p = atomicAdd(&off[d >> BSH], 1);           // LDS rank
    bedges[p] = (s << BSH) | (d & (BSZ - 1));       // src<17b> | dst_lo<8b>
  }
}

// ---- pass 4: per-bucket degree histogram -> dinv ---------------------------
__global__ __launch_bounds__(256) void k_deg(const int* __restrict__ bedges,
                                             const int* __restrict__ bucket_base,
                                             const int* __restrict__ bucket_count,
                                             float* __restrict__ dinv, int N) {
  __shared__ int h[BSZ];
  int tid = threadIdx.x, b = blockIdx.x;
  h[tid] = 0;
  __syncthreads();
  int base = bucket_base[b], nE = bucket_count[b];
  for (int i = tid; i < nE; i += 256) atomicAdd(&h[bedges[base + i] & (BSZ - 1)], 1);
  __syncthreads();
  int node = b * BSZ + tid;
  if (node < N) dinv[node] = rsqrtf((float)(h[tid] + 1));
}

// ---- GEMM1 (MFMA): h1s = x @ W1 * dinv[row]   [N,128]@[128,64] -> fp16 -----
__global__ __launch_bounds__(256) void k_gemm1(
    const float* __restrict__ x, const float* __restrict__ W1,
    const float* __restrict__ dinv, __half* __restrict__ h1s, int N) {
  __shared__ _Float16 bf[4 * 4 * 64 * 8];   // [kc=4][ct=4][lane=64][j=8], 16 KB
  const int tid = threadIdx.x;
  for (int idx = tid; idx < 128 * 64; idx += 256) {
    int k = idx >> 6, c = idx & 63;
    int kc = k >> 5, kk = k & 31;
    int chunk = kk >> 3, j = kk & 7;
    int ct = c >> 4, cl = c & 15;
    bf[(((kc * 4 + ct) * 64) + chunk * 16 + cl) * 8 + j] = (_Float16)W1[idx];
  }
  __syncthreads();

  const int lane = tid & 63, wave = tid >> 6;
  const int row0 = blockIdx.x * 64 + wave * 16;
  const int r_a = lane & 15;
  const int chk = lane >> 4;
  const int arow = min(row0 + r_a, N - 1);
  const float* xp = x + szt(arow) * IN_C + chk * 8;

  f32x4 acc[4];
  #pragma unroll
  for (int ct = 0; ct < 4; ++ct) acc[ct] = (f32x4){0.f, 0.f, 0.f, 0.f};

  #pragma unroll
  for (int kc = 0; kc < 4; ++kc) {
    float4 a0 = *reinterpret_cast<const float4*>(xp + kc * 32);
    float4 a1v = *reinterpret_cast<const float4*>(xp + kc * 32 + 4);
    half8 af;
    af[0] = (_Float16)a0.x;  af[1] = (_Float16)a0.y;
    af[2] = (_Float16)a0.z;  af[3] = (_Float16)a0.w;
    af[4] = (_Float16)a1v.x; af[5] = (_Float16)a1v.y;
    af[6] = (_Float16)a1v.z; af[7] = (_Float16)a1v.w;
    #pragma unroll
    for (int ct = 0; ct < 4; ++ct) {
      half8 bfrag = *reinterpret_cast<const half8*>(&bf[(((kc * 4 + ct) * 64) + lane) * 8]);
      acc[ct] = __builtin_amdgcn_mfma_f32_16x16x32_f16(af, bfrag, acc[ct], 0, 0, 0);
    }
  }
  #pragma unroll
  for (int r = 0; r < 4; ++r) {
    int drow = row0 + chk * 4 + r;
    if (drow < N) {
      float di = dinv[drow];
      #pragma unroll
      for (int ct = 0; ct < 4; ++ct)
        h1s[szt(drow) * HID + ct * 16 + r_a] = (__half)(acc[ct][r] * di);
    }
  }
}

// ---- agg1 edge-parallel: per-bucket LDS accum (256 nodes x 64 feat fp32) ---
__global__ __launch_bounds__(512, 1) void k_agg1e(
    const __half2* __restrict__ h1s2, const int* __restrict__ bedges,
    const int* __restrict__ bucket_base, const int* __restrict__ bucket_count,
    const float* __restrict__ dinv, const float2* __restrict__ b1f2,
    __half2* __restrict__ a1_2, int N) {
  __shared__ float acc[BSZ * HID];    // 64 KB
  const int tid = threadIdx.x;
  float4* a4 = (float4*)acc;
  for (int i = tid; i < BSZ * HID / 4; i += 512)
    a4[i] = make_float4(0.f, 0.f, 0.f, 0.f);
  __syncthreads();

  const int b = blockIdx.x;
  const int base = bucket_base[b];
  const int nE = bucket_count[b];
  const int g = tid >> 5;            // 16 groups of 32 lanes
  const int l = tid & 31;            // half2 feature index

  if (nE > 0) {
    int lastE = nE - 1;
    for (int i = g; i < nE; i += 16 * 4) {
      int i0 = i, i1 = i + 16, i2 = i + 32, i3 = i + 48;
      int e0 = bedges[base + min(i0, lastE)];
      int e1 = bedges[base + min(i1, lastE)];
      int e2 = bedges[base + min(i2, lastE)];
      int e3 = bedges[base + min(i3, lastE)];
      __half2 g0 = h1s2[szt(e0 >> BSH) * 32 + l];
      __half2 g1 = h1s2[szt(e1 >> BSH) * 32 + l];
      __half2 g2 = h1s2[szt(e2 >> BSH) * 32 + l];
      __half2 g3 = h1s2[szt(e3 >> BSH) * 32 + l];
      float2 f0 = __half22float2(g0);
      float2 f1 = __half22float2(g1);
      float2 f2 = __half22float2(g2);
      float2 f3 = __half22float2(g3);
      bool k1 = i1 < nE, k2 = i2 < nE, k3 = i3 < nE;
      f1.x = k1 ? f1.x : 0.f; f1.y = k1 ? f1.y : 0.f;
      f2.x = k2 ? f2.x : 0.f; f2.y = k2 ? f2.y : 0.f;
      f3.x = k3 ? f3.x : 0.f; f3.y = k3 ? f3.y : 0.f;
      atomicAdd(&acc[(e0 & (BSZ - 1)) * HID + 2 * l], f0.x);
      atomicAdd(&acc[(e0 & (BSZ - 1)) * HID + 2 * l + 1], f0.y);
      atomicAdd(&acc[(e1 & (BSZ - 1)) * HID + 2 * l], f1.x);
      atomicAdd(&acc[(e1 & (BSZ - 1)) * HID + 2 * l + 1], f1.y);
      atomicAdd(&acc[(e2 & (BSZ - 1)) * HID + 2 * l], f2.x);
      atomicAdd(&acc[(e2 & (BSZ - 1)) * HID + 2 * l + 1], f2.y);
      atomicAdd(&acc[(e3 & (BSZ - 1)) * HID + 2 * l], f3.x);
      atomicAdd(&acc[(e3 & (BSZ - 1)) * HID + 2 * l + 1], f3.y);
    }
  }
  __syncthreads();

  // epilogue: out = relu(dinv[i]*(acc + self) + b1)
  for (int idx = tid; idx < BSZ * 32; idx += 512) {
    int nl = idx >> 5, l2 = idx & 31;
    int node = b * BSZ + nl;
    if (node < N) {
      float2 sf = __half22float2(h1s2[szt(node) * 32 + l2]);
      float ax = acc[nl * HID + 2 * l2] + sf.x;
      float ay = acc[nl * HID + 2 * l2 + 1] + sf.y;
      float di = dinv[node];
      float2 bb = b1f2[l2];
      a1_2[szt(node) * 32 + l2] =
          __floats2half2_rn(fmaxf(di * ax + bb.x, 0.f), fmaxf(di * ay + bb.y, 0.f));
    }
  }
}

// ---- GEMM2 (MFMA): h2s = a1 @ W2 * dinv[row]   [N,64]@[64,32] fp16 ---------
__global__ __launch_bounds__(256) void k_gemm2(
    const __half* __restrict__ a1, const float* __restrict__ W2,
    const float* __restrict__ dinv, __half* __restrict__ h2s, int N) {
  __shared__ _Float16 bf[2 * 2 * 64 * 8];   // 4 KB
  const int tid = threadIdx.x;
  for (int idx = tid; idx < 64 * 32; idx += 256) {
    int k = idx >> 5, c = idx & 31;
    int kc = k >> 5, kk = k & 31;
    int chunk = kk >> 3, j = kk & 7;
    int ct = c >> 4, cl = c & 15;
    bf[(((kc * 2 + ct) * 64) + chunk * 16 + cl) * 8 + j] = (_Float16)W2[idx];
  }
  __syncthreads();

  const int lane = tid & 63, wave = tid >> 6;
  const int row0 = blockIdx.x * 64 + wave * 16;
  const int r_a = lane & 15;
  const int chk = lane >> 4;
  const int arow = min(row0 + r_a, N - 1);
  const _Float16* ap = (const _Float16*)a1 + szt(arow) * HID + chk * 8;

  f32x4 acc[2];
  acc[0] = (f32x4){0.f, 0.f, 0.f, 0.f};
  acc[1] = (f32x4){0.f, 0.f, 0.f, 0.f};
  #pragma unroll
  for (int kc = 0; kc < 2; ++kc) {
    half8 af = *reinterpret_cast<const half8*>(ap + kc * 32);
    #pragma unroll
    for (int ct = 0; ct < 2; ++ct) {
      half8 bfrag = *reinterpret_cast<const half8*>(&bf[(((kc * 2 + ct) * 64) + lane) * 8]);
      acc[ct] = __builtin_amdgcn_mfma_f32_16x16x32_f16(af, bfrag, acc[ct], 0, 0, 0);
    }
  }
  #pragma unroll
  for (int r = 0; r < 4; ++r) {
    int drow = row0 + chk * 4 + r;
    if (drow < N) {
      float di = dinv[drow];
      #pragma unroll
      for (int ct = 0; ct < 2; ++ct)
        h2s[szt(drow) * OUTC + ct * 16 + r_a] = (__half)(acc[ct][r] * di);
    }
  }
}

// ---- agg2 edge-parallel: per-bucket LDS accum (256 nodes x 32 feat fp32) ---
__global__ __launch_bounds__(512) void k_agg2e(
    const __half2* __restrict__ h2s2, const int* __restrict__ bedges,
    const int* __restrict__ bucket_base, const int* __restrict__ bucket_count,
    const float* __restrict__ dinv, const float2* __restrict__ b2f2,
    float2* __restrict__ out2, int N) {
  __shared__ float acc[BSZ * OUTC];   // 32 KB
  const int tid = threadIdx.x;
  float4* a4 = (float4*)acc;
  for (int i = tid; i < BSZ * OUTC / 4; i += 512)
    a4[i] = make_float4(0.f, 0.f, 0.f, 0.f);
  __syncthreads();

  const int b = blockIdx.x;
  const int base = bucket_base[b];
  const int nE = bucket_count[b];
  const int g = tid >> 4;            // 32 groups of 16 lanes
  const int l = tid & 15;            // half2 feature index

  if (nE > 0) {
    int lastE = nE - 1;
    for (int i = g; i < nE; i += 32 * 4) {
      int i1 = i + 32, i2 = i + 64, i3 = i + 96;
      int e0 = bedges[base + min(i, lastE)];
      int e1 = bedges[base + min(i1, lastE)];
      int e2 = bedges[base + min(i2, lastE)];
      int e3 = bedges[base + min(i3, lastE)];
      __half2 g0 = h2s2[szt(e0 >> BSH) * 16 + l];
      __half2 g1 = h2s2[szt(e1 >> BSH) * 16 + l];
      __half2 g2 = h2s2[szt(e2 >> BSH) * 16 + l];
      __half2 g3 = h2s2[szt(e3 >> BSH) * 16 + l];
      float2 f0 = __half22float2(g0);
      float2 f1 = __half22float2(g1);
      float2 f2 = __half22float2(g2);
      float2 f3 = __half22float2(g3);
      bool k1 = i1 < nE, k2 = i2 < nE, k3 = i3 < nE;
      f1.x = k1 ? f1.x : 0.f; f1.y = k1 ? f1.y : 0.f;
      f2.x = k2 ? f2.x : 0.f; f2.y = k2 ? f2.y : 0.f;
      f3.x = k3 ? f3.x : 0.f; f3.y = k3 ? f3.y : 0.f;
      atomicAdd(&acc[(e0 & (BSZ - 1)) * OUTC + 2 * l], f0.x);
      atomicAdd(&acc[(e0 & (BSZ - 1)) * OUTC + 2 * l + 1], f0.y);
      atomicAdd(&acc[(e1 & (BSZ - 1)) * OUTC + 2 * l], f1.x);
      atomicAdd(&acc[(e1 & (BSZ - 1)) * OUTC + 2 * l + 1], f1.y);
      atomicAdd(&acc[(e2 & (BSZ - 1)) * OUTC + 2 * l], f2.x);
      atomicAdd(&acc[(e2 & (BSZ - 1)) * OUTC + 2 * l + 1], f2.y);
      atomicAdd(&acc[(e3 & (BSZ - 1)) * OUTC + 2 * l], f3.x);
      atomicAdd(&acc[(e3 & (BSZ - 1)) * OUTC + 2 * l + 1], f3.y);
    }
  }
  __syncthreads();

  for (int idx = tid; idx < BSZ * 16; idx += 512) {
    int nl = idx >> 4, l2 = idx & 15;
    int node = b * BSZ + nl;
    if (node < N) {
      float2 sf = __half22float2(h2s2[szt(node) * 16 + l2]);
      float ax = acc[nl * OUTC + 2 * l2] + sf.x;
      float ay = acc[nl * OUTC + 2 * l2 + 1] + sf.y;
      float di = dinv[node];
      float2 bb = b2f2[l2];
      out2[szt(node) * 16 + l2] = make_float2(di * ax + bb.x, di * ay + bb.y);
    }
  }
}

extern "C" void kernel_launch(void* const* d_in, const int* in_sizes, int n_in,
                              void* d_out, int out_size, void* d_ws, size_t ws_size,
                              hipStream_t stream) {
  const float* x  = (const float*)d_in[0];
  const int*   ei = (const int*)d_in[1];
  const float* W1 = (const float*)d_in[2];
  const float* b1 = (const float*)d_in[3];
  const float* W2 = (const float*)d_in[4];
  const float* b2 = (const float*)d_in[5];
  float* out = (float*)d_out;

  const int N = in_sizes[0] / IN_C;
  const int E = in_sizes[1] / 2;
  const int* src = ei;
  const int* dst = ei + E;

  const int B   = (E + EPB - 1) / EPB;        // hist/scatter blocks
  const int NBK = (N + BSZ - 1) / BSZ;        // buckets (<= NSLOT)

  char* ws = (char*)d_ws;
  size_t off = 0;
  auto alloc = [&](size_t bytes) {
    off = (off + 255) & ~(size_t)255;
    void* p = ws + off;
    off += bytes;
    return p;
  };
  int*    hist   = (int*)alloc(szt(B) * NSLOT * 4);
  int*    bbase  = (int*)alloc(NSLOT * 4);
  int*    bcount = (int*)alloc(NSLOT * 4);
  float*  dinv   = (float*)alloc(szt(N) * 4);
  int*    bedges = (int*)alloc(szt(E) * 4);
  __half* h1s    = (__half*)alloc(szt(N) * HID * 2);
  __half* a1     = (__half*)alloc(szt(N) * HID * 2);
  __half* h2s    = (__half*)alloc(szt(N) * OUTC * 2);
  (void)ws_size;

  k_hist<<<B, 256, 0, stream>>>(dst, E, hist);
  k_scan<<<1, 256, 0, stream>>>(hist, B, bbase, bcount);
  k_scatter<<<B, 256, 0, stream>>>(src, dst, E, hist, bbase, bedges);
  k_deg<<<NBK, 256, 0, stream>>>(bedges, bbase, bcount, dinv, N);
  k_gemm1<<<(N + 63) / 64, 256, 0, stream>>>(x, W1, dinv, h1s, N);
  k_agg1e<<<NBK, 512, 0, stream>>>(
      (const __half2*)h1s, bedges, bbase, bcount, dinv, (const float2*)b1,
      (__half2*)a1, N);
  k_gemm2<<<(N + 63) / 64, 256, 0, stream>>>(a1, W2, dinv, h2s, N);
  k_agg2e<<<NBK, 512, 0, stream>>>(
      (const __half2*)h2s, bedges, bbase, bcount, dinv, (const float2*)b2,
      (float2*)out, N);
}

// Round 7
// 127.445 us; speedup vs baseline: 8.8743x; 8.8743x over previous
//
#include <hip/hip_runtime.h>
#include <hip/hip_fp16.h>

// GCN 2-layer: x[N,128] -> (x@W1) agg -> relu -> (@W2) agg -> out[N,32]
// agg[i] = dinv[i] * sum_{j in in(i) + self} h[j]*dinv[j]  (+ bias)
// CSR via 2-level counting sort (no global atomics). Hidden tensors fp16.
// GEMMs on MFMA (16x16x32 f16). Aggs: 8/4 lanes-per-node half8 gather pipelines.

#define IN_C 128
#define HID 64
#define OUTC 32
#define BSH 9            // bucket shift (512 nodes per bucket)
#define BSZ 512
#define NSLOT 256        // bucket slots (>= #buckets = 196)
#define EPB 8192         // edges per histogram/scatter block

typedef _Float16 half8 __attribute__((ext_vector_type(8)));
typedef float f32x4 __attribute__((ext_vector_type(4)));

static __host__ __device__ __forceinline__ size_t szt(int a) { return (size_t)a; }

// ---- pass 1: per-block bucket histograms -----------------------------------
__global__ __launch_bounds__(256) void k_hist(const int* __restrict__ dst, int E,
                                              int* __restrict__ hist) {
  __shared__ int h[NSLOT];
  int tid = threadIdx.x;
  h[tid] = 0;
  __syncthreads();
  int e0 = blockIdx.x * EPB;
  int e1 = min(e0 + EPB, E);
  for (int i = e0 + tid; i < e1; i += 256) atomicAdd(&h[dst[i] >> BSH], 1);
  __syncthreads();
  hist[blockIdx.x * NSLOT + tid] = h[tid];
}

// ---- pass 2a: parallel column scan (one block per bucket slot) -------------
__global__ __launch_bounds__(256) void k_scan_col(int* __restrict__ hist, int B,
                                                  int* __restrict__ bucket_count) {
  __shared__ int sc[256];
  int k = blockIdx.x, t = threadIdx.x;
  int v = (t < B) ? hist[t * NSLOT + k] : 0;
  sc[t] = v;
  __syncthreads();
  for (int o = 1; o < 256; o <<= 1) {   // inclusive Hillis-Steele
    int w = (t >= o) ? sc[t - o] : 0;
    __syncthreads();
    sc[t] += w;
    __syncthreads();
  }
  if (t < B) hist[t * NSLOT + k] = sc[t] - v;   // exclusive, local
  if (t == 255) bucket_count[k] = sc[255];
}

// ---- pass 2b: scan bucket totals -> bucket bases (1 block) -----------------
__global__ __launch_bounds__(256) void k_scan_base(const int* __restrict__ bucket_count,
                                                   int* __restrict__ bucket_base) {
  __shared__ int sc[256];
  int t = threadIdx.x;
  int v = bucket_count[t];
  sc[t] = v;
  __syncthreads();
  for (int o = 1; o < 256; o <<= 1) {
    int w = (t >= o) ? sc[t - o] : 0;
    __syncthreads();
    sc[t] += w;
    __syncthreads();
  }
  bucket_base[t] = sc[t] - v;           // exclusive
}

// ---- pass 3: scatter packed edges to per-(block,bucket) reserved ranges ----
__global__ __launch_bounds__(256) void k_scatter(const int* __restrict__ src,
                                                 const int* __restrict__ dst, int E,
                                                 const int* __restrict__ hist,
                                                 const int* __restrict__ bucket_base,
                                                 int* __restrict__ bedges) {
  __shared__ int off[NSLOT];
  int tid = threadIdx.x;
  off[tid] = hist[blockIdx.x * NSLOT + tid] + bucket_base[tid];
  __syncthreads();
  int e0 = blockIdx.x * EPB;
  int e1 = min(e0 + EPB, E);
  for (int i = e0 + tid; i < e1; i += 256) {
    int d = dst[i], s = src[i];
    int p = atomicAdd(&off[d >> BSH], 1);           // LDS rank
    bedges[p] = (s << BSH) | (d & (BSZ - 1));       // src<17b> | dst_lo<9b>
  }
}

// ---- pass 4: in-LDS counting sort within bucket -> csr/rd/dinv -------------
__global__ __launch_bounds__(256) void k_bucket(const int* __restrict__ bedges,
                                                const int* __restrict__ bucket_base,
                                                const int* __restrict__ bucket_count,
                                                int2* __restrict__ rd,
                                                float* __restrict__ dinv,
                                                int* __restrict__ csr, int N) {
  __shared__ int h[BSZ];
  __shared__ int pfx[BSZ];
  __shared__ int cnt[BSZ];
  __shared__ int sc[256];
  int tid = threadIdx.x;
  int b = blockIdx.x;
  int base = bucket_base[b];
  int nE = bucket_count[b];
  h[tid] = 0; h[tid + 256] = 0;
  cnt[tid] = 0; cnt[tid + 256] = 0;
  __syncthreads();
  for (int i = tid; i < nE; i += 256) atomicAdd(&h[bedges[base + i] & (BSZ - 1)], 1);
  __syncthreads();
  int a0 = h[2 * tid], a1 = h[2 * tid + 1];
  int s = a0 + a1;
  sc[tid] = s;
  __syncthreads();
  for (int o = 1; o < 256; o <<= 1) {
    int v = (tid >= o) ? sc[tid - o] : 0;
    __syncthreads();
    sc[tid] += v;
    __syncthreads();
  }
  int ex = sc[tid] - s;
  pfx[2 * tid] = ex;
  pfx[2 * tid + 1] = ex + a0;
  __syncthreads();
  for (int i = tid; i < BSZ; i += 256) {
    int node = b * BSZ + i;
    if (node < N) {
      int dg = h[i];
      rd[node] = make_int2(base + pfx[i], dg);
      dinv[node] = rsqrtf((float)(dg + 1));
    }
  }
  for (int i = tid; i < nE; i += 256) {
    int e = bedges[base + i];
    int l = e & (BSZ - 1);
    int p = pfx[l] + atomicAdd(&cnt[l], 1);
    csr[base + p] = e >> BSH;
  }
}

// ---- GEMM1 (MFMA): h1s = x @ W1 * dinv[row]   [N,128]@[128,64] -> fp16 -----
__global__ __launch_bounds__(256) void k_gemm1(
    const float* __restrict__ x, const float* __restrict__ W1,
    const float* __restrict__ dinv, __half* __restrict__ h1s, int N) {
  __shared__ _Float16 bf[4 * 4 * 64 * 8];   // [kc=4][ct=4][lane=64][j=8], 16 KB
  const int tid = threadIdx.x;
  for (int idx = tid; idx < 128 * 64; idx += 256) {
    int k = idx >> 6, c = idx & 63;
    int kc = k >> 5, kk = k & 31;
    int chunk = kk >> 3, j = kk & 7;
    int ct = c >> 4, cl = c & 15;
    bf[(((kc * 4 + ct) * 64) + chunk * 16 + cl) * 8 + j] = (_Float16)W1[idx];
  }
  __syncthreads();

  const int lane = tid & 63, wave = tid >> 6;
  const int row0 = blockIdx.x * 64 + wave * 16;
  const int r_a = lane & 15;
  const int chk = lane >> 4;
  const int arow = min(row0 + r_a, N - 1);
  const float* xp = x + szt(arow) * IN_C + chk * 8;

  f32x4 acc[4];
  #pragma unroll
  for (int ct = 0; ct < 4; ++ct) acc[ct] = (f32x4){0.f, 0.f, 0.f, 0.f};

  #pragma unroll
  for (int kc = 0; kc < 4; ++kc) {
    float4 a0 = *reinterpret_cast<const float4*>(xp + kc * 32);
    float4 a1v = *reinterpret_cast<const float4*>(xp + kc * 32 + 4);
    half8 af;
    af[0] = (_Float16)a0.x;  af[1] = (_Float16)a0.y;
    af[2] = (_Float16)a0.z;  af[3] = (_Float16)a0.w;
    af[4] = (_Float16)a1v.x; af[5] = (_Float16)a1v.y;
    af[6] = (_Float16)a1v.z; af[7] = (_Float16)a1v.w;
    #pragma unroll
    for (int ct = 0; ct < 4; ++ct) {
      half8 bfrag = *reinterpret_cast<const half8*>(&bf[(((kc * 4 + ct) * 64) + lane) * 8]);
      acc[ct] = __builtin_amdgcn_mfma_f32_16x16x32_f16(af, bfrag, acc[ct], 0, 0, 0);
    }
  }
  #pragma unroll
  for (int r = 0; r < 4; ++r) {
    int drow = row0 + chk * 4 + r;
    if (drow < N) {
      float di = dinv[drow];
      #pragma unroll
      for (int ct = 0; ct < 4; ++ct)
        h1s[szt(drow) * HID + ct * 16 + r_a] = (__half)(acc[ct][r] * di);
    }
  }
}

// ---- agg1: 8 lanes/node, half8 slices, 8-deep pipelined gathers ------------
__global__ __launch_bounds__(256) void k_agg1(
    const __half* __restrict__ h1s, const int* __restrict__ csr,
    const int2* __restrict__ rd, const float* __restrict__ dinv,
    const float* __restrict__ b1, __half* __restrict__ a1, int N) {
  const int tid = threadIdx.x;
  int node = blockIdx.x * 32 + (tid >> 3);
  if (node >= N) return;
  const int l = tid & 7;
  const int g0 = (tid & 63) & ~7;
  const _Float16* hp = (const _Float16*)h1s;

  half8 selfv = *reinterpret_cast<const half8*>(hp + szt(node) * HID + l * 8);
  float acc[8];
  #pragma unroll
  for (int q = 0; q < 8; ++q) acc[q] = (float)selfv[q];

  int2 v = rd[node];
  int base = v.x, cnt = v.y;
  if (cnt > 0) {
    int last = base + cnt - 1;
    int myidx = csr[min(base + l, last)];
    for (int j = 0; j < cnt; j += 8) {
      int id[8];
      #pragma unroll
      for (int u = 0; u < 8; ++u) id[u] = __shfl(myidx, g0 + u);
      half8 gv[8];
      #pragma unroll
      for (int u = 0; u < 8; ++u)
        gv[u] = *reinterpret_cast<const half8*>(hp + szt(id[u]) * HID + l * 8);
      int jn = j + 8;
      if (jn < cnt) myidx = csr[min(base + jn + l, last)];
      #pragma unroll
      for (int u = 0; u < 8; ++u) {
        bool ok = (j + u) < cnt;
        #pragma unroll
        for (int q = 0; q < 8; ++q) acc[q] += ok ? (float)gv[u][q] : 0.0f;
      }
    }
  }
  float di = dinv[node];
  float4 bb0 = *reinterpret_cast<const float4*>(b1 + l * 8);
  float4 bb1 = *reinterpret_cast<const float4*>(b1 + l * 8 + 4);
  half8 o;
  o[0] = (_Float16)fmaxf(di * acc[0] + bb0.x, 0.f);
  o[1] = (_Float16)fmaxf(di * acc[1] + bb0.y, 0.f);
  o[2] = (_Float16)fmaxf(di * acc[2] + bb0.z, 0.f);
  o[3] = (_Float16)fmaxf(di * acc[3] + bb0.w, 0.f);
  o[4] = (_Float16)fmaxf(di * acc[4] + bb1.x, 0.f);
  o[5] = (_Float16)fmaxf(di * acc[5] + bb1.y, 0.f);
  o[6] = (_Float16)fmaxf(di * acc[6] + bb1.z, 0.f);
  o[7] = (_Float16)fmaxf(di * acc[7] + bb1.w, 0.f);
  *reinterpret_cast<half8*>((_Float16*)a1 + szt(node) * HID + l * 8) = o;
}

// ---- GEMM2 (MFMA): h2s = a1 @ W2 * dinv[row]   [N,64]@[64,32] fp16 ---------
__global__ __launch_bounds__(256) void k_gemm2(
    const __half* __restrict__ a1, const float* __restrict__ W2,
    const float* __restrict__ dinv, __half* __restrict__ h2s, int N) {
  __shared__ _Float16 bf[2 * 2 * 64 * 8];   // 4 KB
  const int tid = threadIdx.x;
  for (int idx = tid; idx < 64 * 32; idx += 256) {
    int k = idx >> 5, c = idx & 31;
    int kc = k >> 5, kk = k & 31;
    int chunk = kk >> 3, j = kk & 7;
    int ct = c >> 4, cl = c & 15;
    bf[(((kc * 2 + ct) * 64) + chunk * 16 + cl) * 8 + j] = (_Float16)W2[idx];
  }
  __syncthreads();

  const int lane = tid & 63, wave = tid >> 6;
  const int row0 = blockIdx.x * 64 + wave * 16;
  const int r_a = lane & 15;
  const int chk = lane >> 4;
  const int arow = min(row0 + r_a, N - 1);
  const _Float16* ap = (const _Float16*)a1 + szt(arow) * HID + chk * 8;

  f32x4 acc[2];
  acc[0] = (f32x4){0.f, 0.f, 0.f, 0.f};
  acc[1] = (f32x4){0.f, 0.f, 0.f, 0.f};
  #pragma unroll
  for (int kc = 0; kc < 2; ++kc) {
    half8 af = *reinterpret_cast<const half8*>(ap + kc * 32);
    #pragma unroll
    for (int ct = 0; ct < 2; ++ct) {
      half8 bfrag = *reinterpret_cast<const half8*>(&bf[(((kc * 2 + ct) * 64) + lane) * 8]);
      acc[ct] = __builtin_amdgcn_mfma_f32_16x16x32_f16(af, bfrag, acc[ct], 0, 0, 0);
    }
  }
  #pragma unroll
  for (int r = 0; r < 4; ++r) {
    int drow = row0 + chk * 4 + r;
    if (drow < N) {
      float di = dinv[drow];
      #pragma unroll
      for (int ct = 0; ct < 2; ++ct)
        h2s[szt(drow) * OUTC + ct * 16 + r_a] = (__half)(acc[ct][r] * di);
    }
  }
}

// ---- agg2: 4 lanes/node, half8 slices, 8-deep pipelined gathers ------------
__global__ __launch_bounds__(256) void k_agg2(
    const __half* __restrict__ h2s, const int* __restrict__ csr,
    const int2* __restrict__ rd, const float* __restrict__ dinv,
    const float* __restrict__ b2, float* __restrict__ out, int N) {
  const int tid = threadIdx.x;
  int node = blockIdx.x * 64 + (tid >> 2);
  if (node >= N) return;
  const int l = tid & 3;
  const int g0 = (tid & 63) & ~3;
  const _Float16* hp = (const _Float16*)h2s;

  half8 selfv = *reinterpret_cast<const half8*>(hp + szt(node) * OUTC + l * 8);
  float acc[8];
  #pragma unroll
  for (int q = 0; q < 8; ++q) acc[q] = (float)selfv[q];

  int2 v = rd[node];
  int base = v.x, cnt = v.y;
  if (cnt > 0) {
    int last = base + cnt - 1;
    int myA = csr[min(base + 2 * l, last)];
    int myB = csr[min(base + 2 * l + 1, last)];
    for (int j = 0; j < cnt; j += 8) {
      int id[8];
      #pragma unroll
      for (int u = 0; u < 4; ++u) {
        id[2 * u]     = __shfl(myA, g0 + u);
        id[2 * u + 1] = __shfl(myB, g0 + u);
      }
      half8 gv[8];
      #pragma unroll
      for (int u = 0; u < 8; ++u)
        gv[u] = *reinterpret_cast<const half8*>(hp + szt(id[u]) * OUTC + l * 8);
      int jn = j + 8;
      if (jn < cnt) {
        myA = csr[min(base + jn + 2 * l, last)];
        myB = csr[min(base + jn + 2 * l + 1, last)];
      }
      #pragma unroll
      for (int u = 0; u < 8; ++u) {
        bool ok = (j + u) < cnt;
        #pragma unroll
        for (int q = 0; q < 8; ++q) acc[q] += ok ? (float)gv[u][q] : 0.0f;
      }
    }
  }
  float di = dinv[node];
  float4 bb0 = *reinterpret_cast<const float4*>(b2 + l * 8);
  float4 bb1 = *reinterpret_cast<const float4*>(b2 + l * 8 + 4);
  float4 o0, o1;
  o0.x = di * acc[0] + bb0.x; o0.y = di * acc[1] + bb0.y;
  o0.z = di * acc[2] + bb0.z; o0.w = di * acc[3] + bb0.w;
  o1.x = di * acc[4] + bb1.x; o1.y = di * acc[5] + bb1.y;
  o1.z = di * acc[6] + bb1.z; o1.w = di * acc[7] + bb1.w;
  float* op = out + szt(node) * OUTC + l * 8;
  *reinterpret_cast<float4*>(op) = o0;
  *reinterpret_cast<float4*>(op + 4) = o1;
}

extern "C" void kernel_launch(void* const* d_in, const int* in_sizes, int n_in,
                              void* d_out, int out_size, void* d_ws, size_t ws_size,
                              hipStream_t stream) {
  const float* x  = (const float*)d_in[0];
  const int*   ei = (const int*)d_in[1];
  const float* W1 = (const float*)d_in[2];
  const float* b1 = (const float*)d_in[3];
  const float* W2 = (const float*)d_in[4];
  const float* b2 = (const float*)d_in[5];
  float* out = (float*)d_out;

  const int N = in_sizes[0] / IN_C;
  const int E = in_sizes[1] / 2;
  const int* src = ei;
  const int* dst = ei + E;

  const int B  = (E + EPB - 1) / EPB;       // hist/scatter blocks
  const int K1 = (N + BSZ - 1) / BSZ;       // buckets (<= NSLOT)

  char* ws = (char*)d_ws;
  size_t off = 0;
  auto alloc = [&](size_t bytes) {
    off = (off + 255) & ~(size_t)255;
    void* p = ws + off;
    off += bytes;
    return p;
  };
  int*    hist   = (int*)alloc(szt(B) * NSLOT * 4);
  int*    bbase  = (int*)alloc(NSLOT * 4);
  int*    bcount = (int*)alloc(NSLOT * 4);
  int2*   rd     = (int2*)alloc(szt(N) * 8);
  float*  dinv   = (float*)alloc(szt(N) * 4);
  int*    bedges = (int*)alloc(szt(E) * 4);
  int*    csr    = (int*)alloc(szt(E) * 4);
  __half* h1s    = (__half*)alloc(szt(N) * HID * 2);
  __half* a1     = (__half*)alloc(szt(N) * HID * 2);
  __half* h2s    = (__half*)alloc(szt(N) * OUTC * 2);
  (void)ws_size;

  k_hist<<<B, 256, 0, stream>>>(dst, E, hist);
  k_scan_col<<<NSLOT, 256, 0, stream>>>(hist, B, bcount);
  k_scan_base<<<1, 256, 0, stream>>>(bcount, bbase);
  k_scatter<<<B, 256, 0, stream>>>(src, dst, E, hist, bbase, bedges);
  k_bucket<<<K1, 256, 0, stream>>>(bedges, bbase, bcount, rd, dinv, csr, N);
  k_gemm1<<<(N + 63) / 64, 256, 0, stream>>>(x, W1, dinv, h1s, N);
  k_agg1<<<(N + 31) / 32, 256, 0, stream>>>(h1s, csr, rd, dinv, b1, a1, N);
  k_gemm2<<<(N + 63) / 64, 256, 0, stream>>>(a1, W2, dinv, h2s, N);
  k_agg2<<<(N + 63) / 64, 256, 0, stream>>>(h2s, csr, rd, dinv, b2, out, N);
}